// Round 6
// baseline (332.068 us; speedup 1.0000x reference)
//
#include <hip/hip_runtime.h>
#include <hip/hip_bf16.h>

#define BB   2048
#define SS   256
#define NTOK (BB*SS)
#define FIN  3
#define CND  4
#define EMB  4
#define HID  64
#define NC   256
#define TPB  256   // T=4 tokens/thread: block covers 1024 tokens

typedef __attribute__((ext_vector_type(2))) float f32x2;
#define Z2 ((f32x2){0.0f, 0.0f})

// R6: the wall is DS-instruction count per token (2722 b128 x 12cyc x 16
// waves/CU = 218us = R0; pipe-shuffling variants R1/R3/R4/R5 all ~215+-10).
// Only amortization moves it: T=4 tokens/thread halves DS instrs per token
// (one broadcast b128 feeds 16 fmas). Register blocker solved by float2
// TOKEN-PAIR packing: hAB[64]+hCD[64] = 128 VGPR, fmas become v_pk_fma_f32
// (or 2x v_fma -- either way bit-identical per-token trees, since packing is
// across tokens, never within a sum). DS wall -> 274k cyc/CU = 114us.
// Grid 512 = exactly 2 blocks/CU resident -> no tail.
#define OF_EW1T 0        // 512  ([64][8] rows: w0..w6, eb1)
#define OF_DW1T 512      // 512  ([64][8] rows: w0..w7)
#define OF_DB1  1024     // 64
#define OF_EB2  1088     // 64
#define OF_DB2  1152     // 64
#define OF_EW3  1216     // 256
#define OF_DW3T 1472     // 256  ([64][4] rows: w0,w1,w2,0)
#define OF_CB   1728     // 1024
#define OF_CC   2752     // 256
#define OF_EW2F 3008     // 4096 (full [64][64])
#define OF_DW2F 7104     // 4096 (full [64][64])
#define SMEM_F  11200    // 44800 B

// (TPB,2): cap 256 VGPR. Tighter caps spill h[] -> 13x regression (R4 note).
__global__ __launch_bounds__(TPB, 2) void vqvae_fused(
        const float* __restrict__ x, const float* __restrict__ mask,
        const float* __restrict__ cond,
        const float* __restrict__ ew1, const float* __restrict__ eb1,
        const float* __restrict__ ew2, const float* __restrict__ eb2,
        const float* __restrict__ ew3, const float* __restrict__ eb3,
        const float* __restrict__ cb,
        const float* __restrict__ dw1, const float* __restrict__ db1,
        const float* __restrict__ dw2, const float* __restrict__ db2,
        const float* __restrict__ dw3, const float* __restrict__ db3,
        float* __restrict__ out, float* __restrict__ loss_ws) {
    __shared__ float smem[SMEM_F];
    const int tid = threadIdx.x;

    // ---- staging (once per block) ----
    for (int idx = tid; idx < (FIN+CND)*HID; idx += TPB) {
        int i = idx >> 6, j = idx & 63;
        smem[OF_EW1T + j*8 + i] = ew1[idx];
    }
    for (int j = tid; j < HID; j += TPB) smem[OF_EW1T + j*8 + 7] = eb1[j];
    for (int idx = tid; idx < (EMB+CND)*HID; idx += TPB) {
        int i = idx >> 6, j = idx & 63;
        smem[OF_DW1T + j*8 + i] = dw1[idx];
    }
    for (int j = tid; j < HID; j += TPB) smem[OF_DB1 + j] = db1[j];
    for (int j = tid; j < HID; j += TPB) smem[OF_EB2 + j] = eb2[j];
    for (int j = tid; j < HID; j += TPB) smem[OF_DB2 + j] = db2[j];
    for (int i = tid; i < HID*EMB; i += TPB) smem[OF_EW3 + i] = ew3[i];
    for (int j = tid; j < HID; j += TPB) {
        smem[OF_DW3T + j*4 + 0] = dw3[j*FIN + 0];
        smem[OF_DW3T + j*4 + 1] = dw3[j*FIN + 1];
        smem[OF_DW3T + j*4 + 2] = dw3[j*FIN + 2];
        smem[OF_DW3T + j*4 + 3] = 0.0f;
    }
    for (int i = tid; i < NC*EMB; i += TPB) smem[OF_CB + i] = cb[i];
    for (int i = tid; i < HID*HID/4; i += TPB) {
        *(float4*)&smem[OF_EW2F + i*4] = *(const float4*)&ew2[i*4];
        *(float4*)&smem[OF_DW2F + i*4] = *(const float4*)&dw2[i*4];
    }
    {   // cc from GLOBAL cb (no barrier dependency); tid in [0,256) covers NC
        float c0 = cb[tid*EMB+0], c1 = cb[tid*EMB+1];
        float c2 = cb[tid*EMB+2], c3 = cb[tid*EMB+3];
        smem[OF_CC+tid] = ((c0*c0 + c1*c1) + c2*c2) + c3*c3;  // validated order
    }
    __syncthreads();

    // four tokens per thread: n0..n3 in batches 4*blk..4*blk+3
    const int n0 = blockIdx.x * (4*TPB) + tid;
    const int n1 = n0 + TPB;
    const int n2 = n0 + 2*TPB;
    const int n3 = n0 + 3*TPB;
    const float m0 = mask[n0], m1 = mask[n1], m2 = mask[n2], m3 = mask[n3];
    const int bu0 = n0 >> 8;
    const int bu1 = bu0 + 1, bu2 = bu0 + 2, bu3 = bu0 + 3;

    f32x2 xinAB[FIN+CND], xinCD[FIN+CND];
    #pragma unroll
    for (int i = 0; i < FIN; i++) {
        xinAB[i] = (f32x2){x[n0*FIN + i] * m0, x[n1*FIN + i] * m1};
        xinCD[i] = (f32x2){x[n2*FIN + i] * m2, x[n3*FIN + i] * m3};
    }
    #pragma unroll
    for (int i = 0; i < CND; i++) {
        xinAB[FIN+i] = (f32x2){cond[bu0*CND + i] * m0, cond[bu1*CND + i] * m1};
        xinCD[FIN+i] = (f32x2){cond[bu2*CND + i] * m2, cond[bu3*CND + i] * m3};
    }

    // ---- encoder L1: 7 -> 64, relu (validated per-token tree, pk-packed) ----
    f32x2 hAB[HID], hCD[HID];
    #pragma unroll
    for (int j = 0; j < HID; j++) {
        float4 lo = *(const float4*)&smem[OF_EW1T + j*8 + 0];
        float4 hi = *(const float4*)&smem[OF_EW1T + j*8 + 4];
        f32x2 a = xinAB[0] * lo.x;
        f32x2 c = xinCD[0] * lo.x;
        a = xinAB[1]*lo.y + a;  c = xinCD[1]*lo.y + c;
        a = xinAB[2]*lo.z + a;  c = xinCD[2]*lo.z + c;
        a = xinAB[3]*lo.w + a;  c = xinCD[3]*lo.w + c;
        a = xinAB[4]*hi.x + a;  c = xinCD[4]*hi.x + c;
        a = xinAB[5]*hi.y + a;  c = xinCD[5]*hi.y + c;
        a = xinAB[6]*hi.z + a;  c = xinCD[6]*hi.z + c;
        f32x2 ta = a + hi.w, tc = c + hi.w;
        hAB[j] = (f32x2){fmaxf(ta.x, 0.0f), fmaxf(ta.y, 0.0f)};
        hCD[j] = (f32x2){fmaxf(tc.x, 0.0f), fmaxf(tc.y, 0.0f)};
    }

    // ---- encoder L2 (relu) fused with L3 fold (validated trees, packed) ----
    f32x2 z0AB = Z2, z1AB = Z2, z2AB = Z2, z3AB = Z2;
    f32x2 z0CD = Z2, z1CD = Z2, z2CD = Z2, z3CD = Z2;
    for (int jt = 0; jt < 16; jt++) {
        f32x2 a0 = Z2, a1 = Z2, a2 = Z2, a3 = Z2;
        f32x2 c0 = Z2, c1 = Z2, c2 = Z2, c3 = Z2;
        #pragma unroll
        for (int k = 0; k < HID; k++) {
            float4 w = *(const float4*)&smem[OF_EW2F + k*HID + jt*4];
            f32x2 hab = hAB[k], hcd = hCD[k];
            a0 = hab*w.x + a0;  a1 = hab*w.y + a1;
            a2 = hab*w.z + a2;  a3 = hab*w.w + a3;
            c0 = hcd*w.x + c0;  c1 = hcd*w.y + c1;
            c2 = hcd*w.z + c2;  c3 = hcd*w.w + c3;
        }
        float4 bb = *(const float4*)&smem[OF_EB2 + jt*4];
        f32x2 s0 = a0 + bb.x, s1 = a1 + bb.y, s2 = a2 + bb.z, s3 = a3 + bb.w;
        f32x2 u0 = c0 + bb.x, u1 = c1 + bb.y, u2 = c2 + bb.z, u3 = c3 + bb.w;
        f32x2 ta0 = (f32x2){fmaxf(s0.x,0.f), fmaxf(s0.y,0.f)};
        f32x2 ta1 = (f32x2){fmaxf(s1.x,0.f), fmaxf(s1.y,0.f)};
        f32x2 ta2 = (f32x2){fmaxf(s2.x,0.f), fmaxf(s2.y,0.f)};
        f32x2 ta3 = (f32x2){fmaxf(s3.x,0.f), fmaxf(s3.y,0.f)};
        f32x2 tc0 = (f32x2){fmaxf(u0.x,0.f), fmaxf(u0.y,0.f)};
        f32x2 tc1 = (f32x2){fmaxf(u1.x,0.f), fmaxf(u1.y,0.f)};
        f32x2 tc2 = (f32x2){fmaxf(u2.x,0.f), fmaxf(u2.y,0.f)};
        f32x2 tc3 = (f32x2){fmaxf(u3.x,0.f), fmaxf(u3.y,0.f)};
        float4 w0 = *(const float4*)&smem[OF_EW3 + (jt*4+0)*EMB];
        z0AB = ta0*w0.x + z0AB; z1AB = ta0*w0.y + z1AB;
        z2AB = ta0*w0.z + z2AB; z3AB = ta0*w0.w + z3AB;
        z0CD = tc0*w0.x + z0CD; z1CD = tc0*w0.y + z1CD;
        z2CD = tc0*w0.z + z2CD; z3CD = tc0*w0.w + z3CD;
        float4 w1 = *(const float4*)&smem[OF_EW3 + (jt*4+1)*EMB];
        z0AB = ta1*w1.x + z0AB; z1AB = ta1*w1.y + z1AB;
        z2AB = ta1*w1.z + z2AB; z3AB = ta1*w1.w + z3AB;
        z0CD = tc1*w1.x + z0CD; z1CD = tc1*w1.y + z1CD;
        z2CD = tc1*w1.z + z2CD; z3CD = tc1*w1.w + z3CD;
        float4 w2 = *(const float4*)&smem[OF_EW3 + (jt*4+2)*EMB];
        z0AB = ta2*w2.x + z0AB; z1AB = ta2*w2.y + z1AB;
        z2AB = ta2*w2.z + z2AB; z3AB = ta2*w2.w + z3AB;
        z0CD = tc2*w2.x + z0CD; z1CD = tc2*w2.y + z1CD;
        z2CD = tc2*w2.z + z2CD; z3CD = tc2*w2.w + z3CD;
        float4 w3 = *(const float4*)&smem[OF_EW3 + (jt*4+3)*EMB];
        z0AB = ta3*w3.x + z0AB; z1AB = ta3*w3.y + z1AB;
        z2AB = ta3*w3.z + z2AB; z3AB = ta3*w3.w + z3AB;
        z0CD = tc3*w3.x + z0CD; z1CD = tc3*w3.y + z1CD;
        z2CD = tc3*w3.z + z2CD; z3CD = tc3*w3.w + z3CD;
    }
    z0AB = z0AB + eb3[0]; z1AB = z1AB + eb3[1];
    z2AB = z2AB + eb3[2]; z3AB = z3AB + eb3[3];
    z0CD = z0CD + eb3[0]; z1CD = z1CD + eb3[1];
    z2CD = z2CD + eb3[2]; z3CD = z3CD + eb3[3];

    // ---- VQ argmin, 4 tokens (validated tree; strict < = np first-min) ----
    const f32x2 zzAB = ((z0AB*z0AB + z1AB*z1AB) + z2AB*z2AB) + z3AB*z3AB;
    const f32x2 zzCD = ((z0CD*z0CD + z1CD*z1CD) + z2CD*z2CD) + z3CD*z3CD;
    float bestA = 3.4e38f, bestB = 3.4e38f, bestC = 3.4e38f, bestD = 3.4e38f;
    int   biA = 0, biB = 0, biC = 0, biD = 0;
    #pragma unroll 2
    for (int ci = 0; ci < NC; ci++) {
        float4 c = *(const float4*)&smem[OF_CB + ci*EMB];
        float cc = smem[OF_CC + ci];
        f32x2 dotAB = z0AB * c.x;
        dotAB = z1AB*c.y + dotAB;
        dotAB = z2AB*c.z + dotAB;
        dotAB = z3AB*c.w + dotAB;
        f32x2 dAB = (zzAB - 2.0f*dotAB) + cc;
        if (dAB.x < bestA) { bestA = dAB.x; biA = ci; }
        if (dAB.y < bestB) { bestB = dAB.y; biB = ci; }
        f32x2 dotCD = z0CD * c.x;
        dotCD = z1CD*c.y + dotCD;
        dotCD = z2CD*c.z + dotCD;
        dotCD = z3CD*c.w + dotCD;
        f32x2 dCD = (zzCD - 2.0f*dotCD) + cc;
        if (dCD.x < bestC) { bestC = dCD.x; biC = ci; }
        if (dCD.y < bestD) { bestD = dCD.y; biD = ci; }
    }
    float4 qA = *(const float4*)&smem[OF_CB + biA*EMB];
    float4 qB = *(const float4*)&smem[OF_CB + biB*EMB];
    float4 qC = *(const float4*)&smem[OF_CB + biC*EMB];
    float4 qD = *(const float4*)&smem[OF_CB + biD*EMB];

    // ---- vq loss partial (atomic order arbitrary; huge threshold slack) ----
    {
        float e0 = z0AB.x-qA.x, e1 = z1AB.x-qA.y, e2 = z2AB.x-qA.z, e3 = z3AB.x-qA.w;
        float f0 = z0AB.y-qB.x, f1 = z1AB.y-qB.y, f2 = z2AB.y-qB.z, f3 = z3AB.y-qB.w;
        float g0 = z0CD.x-qC.x, g1 = z1CD.x-qC.y, g2 = z2CD.x-qC.z, g3 = z3CD.x-qC.w;
        float h0 = z0CD.y-qD.x, h1 = z1CD.y-qD.y, h2 = z2CD.y-qD.z, h3 = z3CD.y-qD.w;
        float sq = (((e0*e0 + e1*e1) + e2*e2) + e3*e3)
                 + (((f0*f0 + f1*f1) + f2*f2) + f3*f3)
                 + (((g0*g0 + g1*g1) + g2*g2) + g3*g3)
                 + (((h0*h0 + h1*h1) + h2*h2) + h3*h3);
        #pragma unroll
        for (int off = 32; off > 0; off >>= 1) sq += __shfl_down(sq, off, 64);
        if ((tid & 63) == 0) atomicAdd(loss_ws, sq);
    }

    out[NTOK*FIN + 1 + n0] = (float)biA;
    out[NTOK*FIN + 1 + n1] = (float)biB;
    out[NTOK*FIN + 1 + n2] = (float)biC;
    out[NTOK*FIN + 1 + n3] = (float)biD;

    // ---- decoder input ----
    f32x2 zdAB[EMB+CND], zdCD[EMB+CND];
    zdAB[0] = (f32x2){qA.x*m0, qB.x*m1};
    zdAB[1] = (f32x2){qA.y*m0, qB.y*m1};
    zdAB[2] = (f32x2){qA.z*m0, qB.z*m1};
    zdAB[3] = (f32x2){qA.w*m0, qB.w*m1};
    zdCD[0] = (f32x2){qC.x*m2, qD.x*m3};
    zdCD[1] = (f32x2){qC.y*m2, qD.y*m3};
    zdCD[2] = (f32x2){qC.z*m2, qD.z*m3};
    zdCD[3] = (f32x2){qC.w*m2, qD.w*m3};
    #pragma unroll
    for (int i = 0; i < CND; i++) {
        zdAB[EMB+i] = (f32x2){cond[bu0*CND + i] * m0, cond[bu1*CND + i] * m1};
        zdCD[EMB+i] = (f32x2){cond[bu2*CND + i] * m2, cond[bu3*CND + i] * m3};
    }

    // ---- decoder L1: 8 -> 64, relu (validated tree, packed; h reused) ----
    #pragma unroll
    for (int j = 0; j < HID; j++) {
        float4 lo = *(const float4*)&smem[OF_DW1T + j*8 + 0];
        float4 hi = *(const float4*)&smem[OF_DW1T + j*8 + 4];
        f32x2 a = zdAB[0] * lo.x;
        f32x2 c = zdCD[0] * lo.x;
        a = zdAB[1]*lo.y + a;  c = zdCD[1]*lo.y + c;
        a = zdAB[2]*lo.z + a;  c = zdCD[2]*lo.z + c;
        a = zdAB[3]*lo.w + a;  c = zdCD[3]*lo.w + c;
        a = zdAB[4]*hi.x + a;  c = zdCD[4]*hi.x + c;
        a = zdAB[5]*hi.y + a;  c = zdCD[5]*hi.y + c;
        a = zdAB[6]*hi.z + a;  c = zdCD[6]*hi.z + c;
        a = zdAB[7]*hi.w + a;  c = zdCD[7]*hi.w + c;
        float bias = smem[OF_DB1 + j];
        f32x2 ta = a + bias, tc = c + bias;
        hAB[j] = (f32x2){fmaxf(ta.x, 0.0f), fmaxf(ta.y, 0.0f)};
        hCD[j] = (f32x2){fmaxf(tc.x, 0.0f), fmaxf(tc.y, 0.0f)};
    }

    // ---- decoder L2 (relu) fused with L3 (validated trees, packed) ----
    f32x2 rAB0 = Z2, rAB1 = Z2, rAB2 = Z2;
    f32x2 rCD0 = Z2, rCD1 = Z2, rCD2 = Z2;
    for (int jt = 0; jt < 16; jt++) {
        f32x2 a0 = Z2, a1 = Z2, a2 = Z2, a3 = Z2;
        f32x2 c0 = Z2, c1 = Z2, c2 = Z2, c3 = Z2;
        #pragma unroll
        for (int k = 0; k < HID; k++) {
            float4 w = *(const float4*)&smem[OF_DW2F + k*HID + jt*4];
            f32x2 hab = hAB[k], hcd = hCD[k];
            a0 = hab*w.x + a0;  a1 = hab*w.y + a1;
            a2 = hab*w.z + a2;  a3 = hab*w.w + a3;
            c0 = hcd*w.x + c0;  c1 = hcd*w.y + c1;
            c2 = hcd*w.z + c2;  c3 = hcd*w.w + c3;
        }
        float4 bb = *(const float4*)&smem[OF_DB2 + jt*4];
        f32x2 s0 = a0 + bb.x, s1 = a1 + bb.y, s2 = a2 + bb.z, s3 = a3 + bb.w;
        f32x2 u0 = c0 + bb.x, u1 = c1 + bb.y, u2 = c2 + bb.z, u3 = c3 + bb.w;
        f32x2 ta0 = (f32x2){fmaxf(s0.x,0.f), fmaxf(s0.y,0.f)};
        f32x2 ta1 = (f32x2){fmaxf(s1.x,0.f), fmaxf(s1.y,0.f)};
        f32x2 ta2 = (f32x2){fmaxf(s2.x,0.f), fmaxf(s2.y,0.f)};
        f32x2 ta3 = (f32x2){fmaxf(s3.x,0.f), fmaxf(s3.y,0.f)};
        f32x2 tc0 = (f32x2){fmaxf(u0.x,0.f), fmaxf(u0.y,0.f)};
        f32x2 tc1 = (f32x2){fmaxf(u1.x,0.f), fmaxf(u1.y,0.f)};
        f32x2 tc2 = (f32x2){fmaxf(u2.x,0.f), fmaxf(u2.y,0.f)};
        f32x2 tc3 = (f32x2){fmaxf(u3.x,0.f), fmaxf(u3.y,0.f)};
        #pragma unroll
        for (int jj = 0; jj < 4; jj++) {
            f32x2 ta = (jj==0)?ta0:(jj==1)?ta1:(jj==2)?ta2:ta3;
            f32x2 tc = (jj==0)?tc0:(jj==1)?tc1:(jj==2)?tc2:tc3;
            int j = jt*4 + jj;
            float4 w = *(const float4*)&smem[OF_DW3T + j*4];
            rAB0 = ta*w.x + rAB0;  rCD0 = tc*w.x + rCD0;
            rAB1 = ta*w.y + rAB1;  rCD1 = tc*w.y + rCD1;
            rAB2 = ta*w.z + rAB2;  rCD2 = tc*w.z + rCD2;
        }
    }
    rAB0 = rAB0 + db3[0]; rAB1 = rAB1 + db3[1]; rAB2 = rAB2 + db3[2];
    rCD0 = rCD0 + db3[0]; rCD1 = rCD1 + db3[1]; rCD2 = rCD2 + db3[2];

    out[n0*FIN + 0] = rAB0.x;
    out[n0*FIN + 1] = rAB1.x;
    out[n0*FIN + 2] = rAB2.x;
    out[n1*FIN + 0] = rAB0.y;
    out[n1*FIN + 1] = rAB1.y;
    out[n1*FIN + 2] = rAB2.y;
    out[n2*FIN + 0] = rCD0.x;
    out[n2*FIN + 1] = rCD1.x;
    out[n2*FIN + 2] = rCD2.x;
    out[n3*FIN + 0] = rCD0.y;
    out[n3*FIN + 1] = rCD1.y;
    out[n3*FIN + 2] = rCD2.y;
}

__global__ void finalize_kernel(float* out, const float* loss_ws) {
    out[NTOK*FIN] = 1.25f * loss_ws[0] * (1.0f / (float)(NTOK*EMB));
}

extern "C" void kernel_launch(void* const* d_in, const int* in_sizes, int n_in,
                              void* d_out, int out_size, void* d_ws, size_t ws_size,
                              hipStream_t stream) {
    (void)in_sizes; (void)n_in; (void)ws_size; (void)out_size;
    float* ws = (float*)d_ws;
    hipMemsetAsync(ws, 0, sizeof(float), stream);   // ws re-poisoned each call

    vqvae_fused<<<NTOK/(4*TPB), TPB, 0, stream>>>(
        (const float*)d_in[0], (const float*)d_in[1], (const float*)d_in[2],
        (const float*)d_in[3], (const float*)d_in[4], (const float*)d_in[5],
        (const float*)d_in[6], (const float*)d_in[7], (const float*)d_in[8],
        (const float*)d_in[9], (const float*)d_in[10], (const float*)d_in[11],
        (const float*)d_in[12], (const float*)d_in[13], (const float*)d_in[14],
        (const float*)d_in[15],
        (float*)d_out, ws);

    finalize_kernel<<<1, 1, 0, stream>>>((float*)d_out, ws);
}